// Round 5
// baseline (226.839 us; speedup 1.0000x reference)
//
#include <hip/hip_runtime.h>
#include <hip/hip_bf16.h>

typedef _Float16 f16;
typedef f16 f16x4 __attribute__((ext_vector_type(4)));
typedef f16 f16x8 __attribute__((ext_vector_type(8)));
typedef float f32x4 __attribute__((ext_vector_type(4)));

#define LL   2048
#define LQ   2048
#define LKV  512
#define DD   128
#define BM   128          // q tokens per block (4 waves x 32)
#define BN   64           // kv tokens per iteration
#define PT_STR 72         // halves per Pt row (64 + 8): rows 16B-aligned

// SEMANTICS (validated round 4, absmax 3.9e-3): the reference's row-major
// (B,L,H,D)->(B*H,L,D) reshape scrambles tokens: batch g = 32*b + l_hi,
// token t = (l%64)*32 + h. repeat_interleave'd K/V softmax == softmax over
// the 512 unique tokens. => 64 independent attentions Lq=2048, Lkv=512, D=128
// on CONTIGUOUS 64-row chunks of Q/K/V; output scattered by (t, l_hi).
//
// This round: pre-pass converts K -> f16 rows and V -> f16 TRANSPOSED tiles in
// d_ws; main staging is pure 16B copies into XOR-swizzled unpadded LDS so all
// fragment accesses are single ds_read_b128 at <=2-way conflict.
// Swizzle: 16B granule index cb stored at cb ^ (row & (granules_per_row-1)).

__global__ __launch_bounds__(256)
void prep(const float* __restrict__ kg, const float* __restrict__ vg,
          f16* __restrict__ kws, f16* __restrict__ vtws)
{
    const int kt = blockIdx.x;   // 0..7
    const int g  = blockIdx.y;   // 0..63
    const int bb = g >> 5, lhi = g & 31;
    const int tid = threadIdx.x;
    const float* kb = kg + ((size_t)bb*LL + 64*lhi)*1024 + (size_t)kt*BN*DD;
    const float* vb = vg + ((size_t)bb*LL + 64*lhi)*1024 + (size_t)kt*BN*DD;
    f16* kd = kws  + ((size_t)g*8 + kt)*8192;   // [64][128] f16
    f16* vd = vtws + ((size_t)g*8 + kt)*8192;   // [128][64] f16 (transposed)

    // K: straight cvt copy, coalesced
#pragma unroll
    for (int i = 0; i < 8; ++i) {
        int f = tid + i*256;                 // [0,2048) float4 granules
        float4 x = *(const float4*)(kb + f*4);
        f16x4 h = { (f16)x.x,(f16)x.y,(f16)x.z,(f16)x.w };
        *(f16x4*)(kd + f*4) = h;
    }
    // V: transpose via LDS, then coalesced copy-out
    __shared__ f16 vt[8192];
#pragma unroll
    for (int i = 0; i < 8; ++i) {
        int f = tid + i*256;
        int kvr = f & 63, c4 = f >> 6;
        float4 x = *(const float4*)(vb + (size_t)kvr*DD + c4*4);
        vt[(c4*4+0)*64 + kvr] = (f16)x.x;
        vt[(c4*4+1)*64 + kvr] = (f16)x.y;
        vt[(c4*4+2)*64 + kvr] = (f16)x.z;
        vt[(c4*4+3)*64 + kvr] = (f16)x.w;
    }
    __syncthreads();
#pragma unroll
    for (int i = 0; i < 4; ++i) {
        int f = tid + i*256;                 // [0,1024) 16B granules
        *(f16x8*)(vd + f*8) = *(const f16x8*)(vt + f*8);
    }
}

// MFMA facts: end-to-end-verified 16x16x32 tuple (m89/m90-97/m120):
//   A: lane(ln=lane&15,qd=lane>>4) slot j -> A[m=ln][k=8*qd+j]
//   B: slot j -> B[k=8*qd+j][n=ln]
//   C/D: elem r -> D[row=4*qd+r][col=ln],  D = A*B + C
// Flow: S^T = K*Q^T (softmax axis in registers), P via LDS, O^T = V^T*P^T.
__global__ __launch_bounds__(256, 3)
void fa_fwd(const float* __restrict__ qg,
            const f16* __restrict__ kws,
            const f16* __restrict__ vtws,
            float* __restrict__ og)
{
    // Ks: [64][128] f16 swizzled (16 granules/row, XOR row&15)  = 16384 B
    // Vt: [128][64] f16 swizzled (8 granules/row, XOR row&7)    = 16384 B
    // Pt: [128][72] f16                                          = 18432 B
    __shared__ __align__(16) f16 smem[8192 + 8192 + BM*PT_STR];  // 51200 B
    f16* Ks = smem;
    f16* Vt = smem + 8192;
    f16* Pt = smem + 16384;

    const int tid  = threadIdx.x;
    const int wave = tid >> 6;
    const int lane = tid & 63;
    const int ln   = lane & 15;
    const int qd   = lane >> 4;

    const int qt   = blockIdx.x;        // 0..15
    const int g    = blockIdx.y;        // 0..63
    const int bb   = g >> 5;
    const int lhi  = g & 31;

    const float* qmat = qg + ((size_t)bb*LL + 64*lhi)*4096;      // [2048][128] f32
    const f16* ktiles = kws  + (size_t)g*8*8192;
    const f16* vtiles = vtws + (size_t)g*8*8192;

    const int qbase = qt*BM + wave*32;

    // Q fragments (B-operand of S^T=K*Q^T): frag(nt,kc) slot j = Q''[qbase+16nt+ln][32kc+8qd+j]
    f16x8 qf[2][4];
#pragma unroll
    for (int nt = 0; nt < 2; ++nt) {
        const float* qrow = qmat + (size_t)(qbase + 16*nt + ln)*DD;
#pragma unroll
        for (int kc = 0; kc < 4; ++kc) {
            const float4* qp = (const float4*)(qrow + kc*32 + 8*qd);
            float4 f0 = qp[0], f1 = qp[1];
            f16x8 t = { (f16)f0.x,(f16)f0.y,(f16)f0.z,(f16)f0.w,
                        (f16)f1.x,(f16)f1.y,(f16)f1.z,(f16)f1.w };
            qf[nt][kc] = t;
        }
    }

    f32x4 o[2][8];   // o[nt][dmt][r] = O^T[16*dmt+4*qd+r][q(nt)]
#pragma unroll
    for (int nt = 0; nt < 2; ++nt)
#pragma unroll
        for (int dmt = 0; dmt < 8; ++dmt)
#pragma unroll
            for (int r = 0; r < 4; ++r) o[nt][dmt][r] = 0.0f;

    float mrun[2] = {-1e30f, -1e30f}, lrun[2] = {0.0f, 0.0f};
    const float SC2 = 0.08837890625f * 1.44269504088896340f; // fp16(1/sqrt(128)) * log2e

    for (int kt = 0; kt < LKV/BN; ++kt) {
        const f16* ktile = ktiles + kt*8192;
        const f16* vtile = vtiles + kt*8192;

        // ---- stage K: pure 16B copies into swizzled Ks ----
#pragma unroll
        for (int i = 0; i < 4; ++i) {
            int f = tid + i*256;                  // [0,1024)
            int row = f >> 4, cb = f & 15;
            f16x8 h = *(const f16x8*)(ktile + f*8);
            *(f16x8*)(Ks + row*128 + ((cb ^ (row & 15)) * 8)) = h;
        }
        // ---- stage V^T: pure 16B copies into swizzled Vt ----
#pragma unroll
        for (int i = 0; i < 4; ++i) {
            int f = tid + i*256;
            int row = f >> 3, vb = f & 7;
            f16x8 h = *(const f16x8*)(vtile + f*8);
            *(f16x8*)(Vt + row*64 + ((vb ^ (row & 7)) * 8)) = h;
        }
        __syncthreads();

        // ---- S^T = K*Q^T : 4 kv-tiles x 2 q-tiles, K=128 in 4 chunks ----
        f32x4 st[2][4];  // st[nt][mt][r] = S^T[16*mt+4*qd+r][q(nt)]
#pragma unroll
        for (int nt = 0; nt < 2; ++nt)
#pragma unroll
            for (int mt = 0; mt < 4; ++mt)
#pragma unroll
                for (int r = 0; r < 4; ++r) st[nt][mt][r] = 0.0f;
#pragma unroll
        for (int mt = 0; mt < 4; ++mt) {
            const f16* kr = Ks + (16*mt + ln)*128;
#pragma unroll
            for (int kc = 0; kc < 4; ++kc) {
                f16x8 af = *(const f16x8*)(kr + (((4*kc + qd) ^ ln) * 8));  // b128
#pragma unroll
                for (int nt = 0; nt < 2; ++nt)
                    st[nt][mt] = __builtin_amdgcn_mfma_f32_16x16x32_f16(af, qf[nt][kc], st[nt][mt], 0,0,0);
            }
        }

        // ---- online softmax over kv (in-lane + shfl_xor 16,32) ----
        float alph[2];
#pragma unroll
        for (int nt = 0; nt < 2; ++nt) {
            float mx = -1e30f;
#pragma unroll
            for (int mt = 0; mt < 4; ++mt)
#pragma unroll
                for (int r = 0; r < 4; ++r) {
                    float v = st[nt][mt][r]*SC2; st[nt][mt][r] = v; mx = fmaxf(mx, v);
                }
            mx = fmaxf(mx, __shfl_xor(mx, 16, 64));
            mx = fmaxf(mx, __shfl_xor(mx, 32, 64));
            float mnew = fmaxf(mrun[nt], mx);
            alph[nt] = exp2f(mrun[nt] - mnew);
            float rs = 0.0f;
#pragma unroll
            for (int mt = 0; mt < 4; ++mt)
#pragma unroll
                for (int r = 0; r < 4; ++r) {
                    float p = exp2f(st[nt][mt][r] - mnew);
                    st[nt][mt][r] = p; rs += p;
                }
            rs += __shfl_xor(rs, 16, 64);
            rs += __shfl_xor(rs, 32, 64);
            lrun[nt] = lrun[nt]*alph[nt] + rs;
            mrun[nt] = mnew;
        }

        // ---- P -> LDS (C/D layout, wave-private rows): Pt[q][kv], b64 writes ----
#pragma unroll
        for (int nt = 0; nt < 2; ++nt) {
            f16* prow = Pt + (wave*32 + 16*nt + ln)*PT_STR + 4*qd;
#pragma unroll
            for (int mt = 0; mt < 4; ++mt) {
                f16x4 pp = { (f16)st[nt][mt][0], (f16)st[nt][mt][1],
                             (f16)st[nt][mt][2], (f16)st[nt][mt][3] };
                *(f16x4*)(prow + 16*mt) = pp;
            }
        }

        // ---- rescale O^T by alpha ----
#pragma unroll
        for (int nt = 0; nt < 2; ++nt)
#pragma unroll
            for (int dmt = 0; dmt < 8; ++dmt)
#pragma unroll
                for (int r = 0; r < 4; ++r) o[nt][dmt][r] *= alph[nt];

        // ---- O^T += V^T * P^T : A = swizzled Vt rows, B = own-wave Pt rows ----
#pragma unroll
        for (int kc2 = 0; kc2 < 2; ++kc2) {
            f16x8 pf[2];
#pragma unroll
            for (int nt = 0; nt < 2; ++nt)
                pf[nt] = *(const f16x8*)(Pt + (wave*32 + 16*nt + ln)*PT_STR + kc2*32 + 8*qd);
#pragma unroll
            for (int dmt = 0; dmt < 8; ++dmt) {
                const f16* vr = Vt + (16*dmt + ln)*64;
                f16x8 vf = *(const f16x8*)(vr + (((4*kc2 + qd) ^ (ln & 7)) * 8));
#pragma unroll
                for (int nt = 0; nt < 2; ++nt)
                    o[nt][dmt] = __builtin_amdgcn_mfma_f32_16x16x32_f16(vf, pf[nt], o[nt][dmt], 0,0,0);
            }
        }
        __syncthreads();   // protect Ks/Vt (and Pt) before next staging
    }

    // ---- epilogue: O^T/l -> f32; out[g][t][d] -> og[(bb*2048+t)*4096 + lhi*128 + d] ----
#pragma unroll
    for (int nt = 0; nt < 2; ++nt) {
        float inv = 1.0f / lrun[nt];
        int qtok = qbase + 16*nt + ln;
        float* orow = og + ((size_t)bb*LL + qtok)*4096 + lhi*DD + 4*qd;
#pragma unroll
        for (int dmt = 0; dmt < 8; ++dmt) {
            float4 x = { o[nt][dmt][0]*inv, o[nt][dmt][1]*inv,
                         o[nt][dmt][2]*inv, o[nt][dmt][3]*inv };
            *(float4*)(orow + 16*dmt) = x;
        }
    }
}

extern "C" void kernel_launch(void* const* d_in, const int* in_sizes, int n_in,
                              void* d_out, int out_size, void* d_ws, size_t ws_size,
                              hipStream_t stream) {
    (void)in_sizes; (void)n_in; (void)out_size; (void)ws_size;
    const float* q = (const float*)d_in[0];
    const float* k = (const float*)d_in[1];
    const float* v = (const float*)d_in[2];
    float* o = (float*)d_out;
    f16* kws  = (f16*)d_ws;                     // 64*8*8192 f16 = 8 MB
    f16* vtws = (f16*)d_ws + (size_t)64*8*8192; // 8 MB
    dim3 pgrid(8, 64), pblk(256);
    hipLaunchKernelGGL(prep, pgrid, pblk, 0, stream, k, v, kws, vtws);
    dim3 grid(LQ/BM, 64), block(256);
    hipLaunchKernelGGL(fa_fwd, grid, block, 0, stream, q, kws, vtws, o);
}